// Round 1
// baseline (25834.909 us; speedup 1.0000x reference)
//
#include <hip/hip_runtime.h>
#include <stdint.h>

#define TS 1024
#define NB 32
#define DIN 512
#define HU 768
#define KT 1280           // DIN + HU
#define NWG 96            // workgroups per direction
#define UPW 8             // hidden units per WG

typedef _Float16 f16x8 __attribute__((ext_vector_type(8)));
typedef float f32x16 __attribute__((ext_vector_type(16)));
typedef unsigned int u32;
using gas_u32 = u32 __attribute__((address_space(1)));
using las_u32 = u32 __attribute__((address_space(3)));

__device__ __forceinline__ unsigned short f2h_bits(float f) {
  _Float16 h = (_Float16)f;
  return __builtin_bit_cast(unsigned short, h);
}

// ---------------- init: zero counters and h buffers (buf0 of each dir) ----------------
__global__ void lstm_init_k(u32* hb_fw, u32* hb_bw, u32* cnt) {
  int i = blockIdx.x * 256 + threadIdx.x;
  const int HB = NB * HU / 2;            // 12288 u32 words per h buffer0
  if (i < HB) hb_fw[i] = 0u;
  else if (i < 2 * HB) hb_bw[i - HB] = 0u;
  else if (i < 2 * HB + 2 * TS) cnt[i - 2 * HB] = 0u;
}

// ---------------- transpose + fp16 convert: x[B][T][D] -> xh[T][B][D] ----------------
__global__ void lstm_xpose_k(const float* __restrict__ x, unsigned short* __restrict__ xh) {
  int idx = blockIdx.x * 256 + threadIdx.x;   // one float4 each; total 32*1024*128
  int d4 = idx & 127;
  int t  = (idx >> 7) & 1023;
  int b  = idx >> 17;
  float4 v = *(const float4*)(x + ((size_t)(b * TS + t) * DIN + d4 * 4));
  ushort4 o;
  o.x = f2h_bits(v.x); o.y = f2h_bits(v.y); o.z = f2h_bits(v.z); o.w = f2h_bits(v.w);
  *(ushort4*)(xh + ((size_t)(t * NB + b) * DIN + d4 * 4)) = o;
}

// ---------------- persistent bidirectional LSTM scan ----------------
__global__ __launch_bounds__(256, 1) void lstm_persist_k(
    const float* __restrict__ Wfw, const float* __restrict__ bfw, const float* __restrict__ pfw,
    const float* __restrict__ Wbw, const float* __restrict__ bbw, const float* __restrict__ pbw,
    const unsigned short* __restrict__ xh,
    unsigned short* hb_fw, unsigned short* hb_bw,
    u32* cnt_all, float* __restrict__ out)
{
  const int wg  = blockIdx.x;
  const int dir = (wg >= NWG) ? 1 : 0;
  const int g   = wg - dir * NWG;
  const int u0  = g * UPW;
  const float* W    = dir ? Wbw : Wfw;
  const float* bias = dir ? bbw : bfw;
  const float* peep = dir ? pbw : pfw;
  unsigned short* hbuf = dir ? hb_bw : hb_fw;
  u32* cnt = cnt_all + dir * TS;

  const int tid   = threadIdx.x;
  const int lane  = tid & 63;
  const int wq    = tid >> 6;     // wave id = K quarter (K range [wq*320, wq*320+320))
  const int colc  = lane & 31;    // MFMA col (B-frag) / row (A-frag) lane index
  const int khalf = lane >> 5;

  __shared__ __align__(16) unsigned short Astage[NB * KT];  // 80 KB, [32 rows][160 16B-chunks], swizzled
  __shared__ float part[4][NB][33];                          // padded exchange, ~16.9 KB

  // ---- preload W slice into registers as MFMA B fragments ----
  // local col c: gate = c>>3, unit = u0 + (c&7); global col = gate*768 + unit
  f16x8 wfr[20];
  {
    const int gcol = (colc >> 3) * HU + u0 + (colc & 7);
#pragma unroll
    for (int ks = 0; ks < 20; ++ks) {
      const int k0 = wq * 320 + ks * 16 + khalf * 8;
#pragma unroll
      for (int j = 0; j < 8; ++j) {
        wfr[ks][j] = (_Float16)W[(k0 + j) * 3072 + gcol];
      }
    }
  }

  // ---- per-thread epilogue state: thread owns (batch eb, unit eu) ----
  const int eb = tid >> 3;
  const int eu = tid & 7;
  const int gu = u0 + eu;
  const float b_i = bias[gu], b_j = bias[HU + gu], b_f = bias[2 * HU + gu], b_o = bias[3 * HU + gu];
  const float p_i = peep[gu], p_f = peep[HU + gu], p_o = peep[2 * HU + gu];
  float cst = 0.0f;
  float* outp = out + (size_t)eb * TS * 1536 + dir * HU + gu;

  for (int s = 0; s < TS; ++s) {
    const int t_in = dir ? (TS - 1 - s) : s;
    const unsigned short* __restrict__ hprev = hbuf + (s & 1) * (NB * HU);
    unsigned short* hnext = hbuf + ((s & 1) ^ 1) * (NB * HU);
    const unsigned short* __restrict__ xt = xh + (size_t)t_in * (NB * DIN);

    // ---- stage A = [x_t | h_prev] into LDS, source-swizzled (chunk^=(row&7) on low3) ----
    // x chunks 0..63 : one global_load_lds call per row
#pragma unroll
    for (int cc = 0; cc < 8; ++cc) {
      const int row = wq * 8 + cc;
      const int kc  = (lane & ~7) | ((lane ^ row) & 7);
      __builtin_amdgcn_global_load_lds((const gas_u32*)(xt + row * DIN + kc * 8),
                                       (las_u32*)(&Astage[row * KT]), 16, 0, 0);
    }
    // h chunks 64..127
#pragma unroll
    for (int cc = 0; cc < 8; ++cc) {
      const int row = wq * 8 + cc;
      const int kcs = 64 + lane;
      const int kc  = (kcs & ~7) | ((kcs ^ row) & 7);
      __builtin_amdgcn_global_load_lds((const gas_u32*)(hprev + row * HU + (kc - 64) * 8),
                                       (las_u32*)(&Astage[row * KT + 512]), 16, 0, 0);
    }
    // h chunks 128..159 (manual: dest not lane-contiguous per row)
#pragma unroll
    for (int q = 0; q < 4; ++q) {
      const int idx = q * 256 + tid;          // 0..1023
      const int row = idx >> 5;
      const int kcs = 128 + (idx & 31);
      const int kc  = (kcs & ~7) | ((kcs ^ row) & 7);
      const uint4 v = *(const uint4*)(hprev + row * HU + (kc - 64) * 8);
      *(uint4*)(&Astage[row * KT + kcs * 8]) = v;
    }
    __syncthreads();

    // ---- MFMA: z_quarter[32b x 32c] over K quarter ----
    f32x16 acc;
#pragma unroll
    for (int r = 0; r < 16; ++r) acc[r] = 0.0f;
    const int arow = colc;                    // A-frag row = batch = lane&31
#pragma unroll
    for (int ks = 0; ks < 20; ++ks) {
      const int kc  = wq * 40 + ks * 2 + khalf;
      const int kcs = (kc & ~7) | ((kc ^ arow) & 7);
      const f16x8 a = *(const f16x8*)(&Astage[arow * KT + kcs * 8]);
      acc = __builtin_amdgcn_mfma_f32_32x32x16_f16(a, wfr[ks], acc, 0, 0, 0);
    }
    // C/D layout (verified m74/m101): col=lane&31, row=(r&3)+8*(r>>2)+4*(lane>>5)
#pragma unroll
    for (int r = 0; r < 16; ++r) {
      const int prow = (r & 3) + 8 * (r >> 2) + 4 * khalf;
      part[wq][prow][colc] = acc[r];
    }
    __syncthreads();

    // ---- gates epilogue: reduce 4 K-quarters, peephole LSTM cell ----
    float zi = part[0][eb][eu]      + part[1][eb][eu]      + part[2][eb][eu]      + part[3][eb][eu];
    float zj = part[0][eb][8 + eu]  + part[1][eb][8 + eu]  + part[2][eb][8 + eu]  + part[3][eb][8 + eu];
    float zf = part[0][eb][16 + eu] + part[1][eb][16 + eu] + part[2][eb][16 + eu] + part[3][eb][16 + eu];
    float zo = part[0][eb][24 + eu] + part[1][eb][24 + eu] + part[2][eb][24 + eu] + part[3][eb][24 + eu];
    const float ig = 1.0f / (1.0f + __expf(-(zi + b_i + p_i * cst)));
    const float fg = 1.0f / (1.0f + __expf(-(zf + b_f + 1.0f + p_f * cst)));
    const float jt = 1.0f - 2.0f / (__expf(2.0f * (zj + b_j)) + 1.0f);
    const float cn = fg * cst + ig * jt;
    const float og = 1.0f / (1.0f + __expf(-(zo + b_o + p_o * cn)));
    const float hn = og * (1.0f - 2.0f / (__expf(2.0f * cn) + 1.0f));
    cst = cn;
    hnext[eb * HU + gu] = f2h_bits(hn);
    outp[(size_t)t_in * 1536] = hn;

    // ---- per-direction global barrier ----
    __threadfence();
    __syncthreads();
    if (tid == 0) {
      atomicAdd(cnt + s, 1u);
      while (__hip_atomic_load(cnt + s, __ATOMIC_RELAXED, __HIP_MEMORY_SCOPE_AGENT) < (u32)NWG) {
        __builtin_amdgcn_s_sleep(1);
      }
      __threadfence();
    }
    __syncthreads();
  }
}

extern "C" void kernel_launch(void* const* d_in, const int* in_sizes, int n_in,
                              void* d_out, int out_size, void* d_ws, size_t ws_size,
                              hipStream_t stream) {
  const float* x   = (const float*)d_in[0];
  const float* Wfw = (const float*)d_in[1];
  const float* bfw = (const float*)d_in[2];
  const float* pfw = (const float*)d_in[3];
  const float* Wbw = (const float*)d_in[4];
  const float* bbw = (const float*)d_in[5];
  const float* pbw = (const float*)d_in[6];
  float* out = (float*)d_out;

  char* ws = (char*)d_ws;
  unsigned short* xh   = (unsigned short*)ws;                       // 33,554,432 B
  unsigned short* hbfw = (unsigned short*)(ws + 33554432);          //     98,304 B (2 bufs)
  unsigned short* hbbw = (unsigned short*)(ws + 33554432 + 98304);  //     98,304 B
  u32* cnt             = (u32*)(ws + 33554432 + 2 * 98304);         //      8,192 B

  lstm_init_k<<<104, 256, 0, stream>>>((u32*)hbfw, (u32*)hbbw, cnt);
  lstm_xpose_k<<<16384, 256, 0, stream>>>(x, xh);

  void* kargs[] = {(void*)&Wfw, (void*)&bfw, (void*)&pfw,
                   (void*)&Wbw, (void*)&bbw, (void*)&pbw,
                   (void*)&xh, (void*)&hbfw, (void*)&hbbw,
                   (void*)&cnt, (void*)&out};
  hipError_t err = hipLaunchCooperativeKernel((const void*)lstm_persist_k,
                                              dim3(2 * NWG), dim3(256), kargs, 0, stream);
  if (err != hipSuccess) {
    // fallback: plain launch (192 blocks <= 256 CUs, 1 block/CU by LDS -> co-resident)
    lstm_persist_k<<<dim3(2 * NWG), dim3(256), 0, stream>>>(Wfw, bfw, pfw, Wbw, bbw, pbw,
                                                            xh, hbfw, hbbw, cnt, out);
  }
}

// Round 2
// 6979.807 us; speedup vs baseline: 3.7014x; 3.7014x over previous
//
#include <hip/hip_runtime.h>
#include <stdint.h>

#define TS 1024
#define NB 32
#define DIN 512
#define HU 768
#define KT 1280           // DIN + HU
#define NWG 96            // workgroups per direction
#define UPW 8             // hidden units per WG

typedef _Float16 f16x8 __attribute__((ext_vector_type(8)));
typedef float f32x16 __attribute__((ext_vector_type(16)));
typedef unsigned int u32;
typedef unsigned long long u64;
using gas_u32 = u32 __attribute__((address_space(1)));
using las_u32 = u32 __attribute__((address_space(3)));

__device__ __forceinline__ unsigned short f2h_bits(float f) {
  _Float16 h = (_Float16)f;
  return __builtin_bit_cast(unsigned short, h);
}

// ---------------- init: zero counters and h buffers (buf0 of each dir) ----------------
__global__ void lstm_init_k(u32* hb_fw, u32* hb_bw, u32* cnt) {
  int i = blockIdx.x * 256 + threadIdx.x;
  const int HB = NB * HU / 2;            // 12288 u32 words per h buffer0
  if (i < HB) hb_fw[i] = 0u;
  else if (i < 2 * HB) hb_bw[i - HB] = 0u;
  else if (i < 2 * HB + 2 * TS) cnt[i - 2 * HB] = 0u;
}

// ---------------- transpose + fp16 convert: x[B][T][D] -> xh[T][B][D] ----------------
__global__ void lstm_xpose_k(const float* __restrict__ x, unsigned short* __restrict__ xh) {
  int idx = blockIdx.x * 256 + threadIdx.x;   // one float4 each; total 32*1024*128
  int d4 = idx & 127;
  int t  = (idx >> 7) & 1023;
  int b  = idx >> 17;
  float4 v = *(const float4*)(x + ((size_t)(b * TS + t) * DIN + d4 * 4));
  ushort4 o;
  o.x = f2h_bits(v.x); o.y = f2h_bits(v.y); o.z = f2h_bits(v.z); o.w = f2h_bits(v.w);
  *(ushort4*)(xh + ((size_t)(t * NB + b) * DIN + d4 * 4)) = o;
}

// ---------------- persistent bidirectional LSTM scan ----------------
__global__ __launch_bounds__(256, 1) void lstm_persist_k(
    const float* __restrict__ Wfw, const float* __restrict__ bfw, const float* __restrict__ pfw,
    const float* __restrict__ Wbw, const float* __restrict__ bbw, const float* __restrict__ pbw,
    const unsigned short* __restrict__ xh,
    unsigned short* hb_fw, unsigned short* hb_bw,
    u32* cnt_all, float* __restrict__ out)
{
  const int wg  = blockIdx.x;
  const int dir = (wg >= NWG) ? 1 : 0;
  const int g   = wg - dir * NWG;
  const int u0  = g * UPW;
  const float* W    = dir ? Wbw : Wfw;
  const float* bias = dir ? bbw : bfw;
  const float* peep = dir ? pbw : pfw;
  unsigned short* hbuf = dir ? hb_bw : hb_fw;
  u32* cnt = cnt_all + dir * TS;

  const int tid   = threadIdx.x;
  const int lane  = tid & 63;
  const int wq    = tid >> 6;     // wave id = K quarter (K range [wq*320, wq*320+320))
  const int colc  = lane & 31;    // MFMA col (B-frag) / row (A-frag) lane index
  const int khalf = lane >> 5;

  __shared__ __align__(16) unsigned short Astage[NB * KT];  // 80 KB, [32 rows][160 16B-chunks], swizzled
  __shared__ float part[4][NB][33];                          // padded exchange

  // ---- preload W slice into registers as MFMA B fragments ----
  // local col c: gate = c>>3, unit = u0 + (c&7); global col = gate*768 + unit
  f16x8 wfr[20];
  {
    const int gcol = (colc >> 3) * HU + u0 + (colc & 7);
#pragma unroll
    for (int ks = 0; ks < 20; ++ks) {
      const int k0 = wq * 320 + ks * 16 + khalf * 8;
#pragma unroll
      for (int j = 0; j < 8; ++j) {
        wfr[ks][j] = (_Float16)W[(k0 + j) * 3072 + gcol];
      }
    }
  }

  // ---- per-thread epilogue state: thread owns (batch eb, unit eu) ----
  const int eb = tid >> 3;
  const int eu = tid & 7;
  const int gu = u0 + eu;
  const float b_i = bias[gu], b_j = bias[HU + gu], b_f = bias[2 * HU + gu], b_o = bias[3 * HU + gu];
  const float p_i = peep[gu], p_f = peep[HU + gu], p_o = peep[2 * HU + gu];
  float cst = 0.0f;
  float* outp = out + (size_t)eb * TS * 1536 + dir * HU + gu;
  const int hrow = tid >> 3;      // staging row for h (0..31)
  const int hc0  = tid & 7;       // staging chunk phase

  for (int s = 0; s < TS; ++s) {
    const int t_in = dir ? (TS - 1 - s) : s;
    u64* hp64 = (u64*)(hbuf + (s & 1) * (NB * HU));
    u32* hnext32 = (u32*)(hbuf + (((s & 1) ^ 1)) * (NB * HU));
    const unsigned short* __restrict__ xt = xh + (size_t)t_in * (NB * DIN);

    // ---- stage x part of A into LDS via global_load_lds, source-swizzled ----
#pragma unroll
    for (int cc = 0; cc < 8; ++cc) {
      const int row = wq * 8 + cc;
      const int kc  = (lane & ~7) | ((lane ^ row) & 7);
      __builtin_amdgcn_global_load_lds((const gas_u32*)(xt + row * DIN + kc * 8),
                                       (las_u32*)(&Astage[row * KT]), 16, 0, 0);
    }
    // ---- stage h part: coherent (agent-scope) loads -> swizzled LDS writes ----
    // chunks 64..159 of each row (96 chunks x 16B = 768 fp16)
#pragma unroll
    for (int q = 0; q < 12; ++q) {
      const int c   = hc0 + q * 8;            // 0..95
      const int kcs = 64 + c;
      const int swz = (kcs & ~7) | ((kcs ^ hrow) & 7);
      const u64 lo = __hip_atomic_load(hp64 + hrow * 192 + c * 2,
                                       __ATOMIC_RELAXED, __HIP_MEMORY_SCOPE_AGENT);
      const u64 hi = __hip_atomic_load(hp64 + hrow * 192 + c * 2 + 1,
                                       __ATOMIC_RELAXED, __HIP_MEMORY_SCOPE_AGENT);
      *(u64*)(&Astage[hrow * KT + swz * 8])     = lo;
      *(u64*)(&Astage[hrow * KT + swz * 8 + 4]) = hi;
    }
    __syncthreads();

    // ---- MFMA: z_quarter[32b x 32c] over K quarter, 2 independent chains ----
    f32x16 acc0, acc1;
#pragma unroll
    for (int r = 0; r < 16; ++r) { acc0[r] = 0.0f; acc1[r] = 0.0f; }
    const int arow = colc;                    // A-frag row = batch = lane&31
#pragma unroll
    for (int ks = 0; ks < 20; ks += 2) {
      const int kcA  = wq * 40 + ks * 2 + khalf;
      const int kcsA = (kcA & ~7) | ((kcA ^ arow) & 7);
      const f16x8 a0 = *(const f16x8*)(&Astage[arow * KT + kcsA * 8]);
      acc0 = __builtin_amdgcn_mfma_f32_32x32x16_f16(a0, wfr[ks], acc0, 0, 0, 0);
      const int kcB  = wq * 40 + (ks + 1) * 2 + khalf;
      const int kcsB = (kcB & ~7) | ((kcB ^ arow) & 7);
      const f16x8 a1 = *(const f16x8*)(&Astage[arow * KT + kcsB * 8]);
      acc1 = __builtin_amdgcn_mfma_f32_32x32x16_f16(a1, wfr[ks + 1], acc1, 0, 0, 0);
    }
    // C/D layout: col=lane&31, row=(r&3)+8*(r>>2)+4*(lane>>5)
#pragma unroll
    for (int r = 0; r < 16; ++r) {
      const int prow = (r & 3) + 8 * (r >> 2) + 4 * khalf;
      part[wq][prow][colc] = acc0[r] + acc1[r];
    }
    __syncthreads();

    // ---- gates epilogue: reduce 4 K-quarters, peephole LSTM cell ----
    float zi = part[0][eb][eu]      + part[1][eb][eu]      + part[2][eb][eu]      + part[3][eb][eu];
    float zj = part[0][eb][8 + eu]  + part[1][eb][8 + eu]  + part[2][eb][8 + eu]  + part[3][eb][8 + eu];
    float zf = part[0][eb][16 + eu] + part[1][eb][16 + eu] + part[2][eb][16 + eu] + part[3][eb][16 + eu];
    float zo = part[0][eb][24 + eu] + part[1][eb][24 + eu] + part[2][eb][24 + eu] + part[3][eb][24 + eu];
    const float ig = 1.0f / (1.0f + __expf(-(zi + b_i + p_i * cst)));
    const float fg = 1.0f / (1.0f + __expf(-(zf + b_f + 1.0f + p_f * cst)));
    const float jt = 1.0f - 2.0f / (__expf(2.0f * (zj + b_j)) + 1.0f);
    const float cn = fg * cst + ig * jt;
    const float og = 1.0f / (1.0f + __expf(-(zo + b_o + p_o * cn)));
    const float hn = og * (1.0f - 2.0f / (__expf(2.0f * cn) + 1.0f));
    cst = cn;

    // ---- h store: pack fp16 pair, coherent write-through (no cache fence) ----
    {
      const u32 mine = (u32)f2h_bits(hn);
      const u32 other = (u32)(unsigned)__shfl_xor((int)mine, 1, 64);
      if (!(eu & 1)) {
        const u32 pack = mine | (other << 16);
        __hip_atomic_store(hnext32 + eb * 384 + ((u0 + eu) >> 1), pack,
                           __ATOMIC_RELAXED, __HIP_MEMORY_SCOPE_AGENT);
      }
    }
    outp[(size_t)t_in * 1536] = hn;

    // ---- per-direction global barrier (no threadfence: syncthreads drains vmcnt,
    //      so all agent-scope h stores are acked at the coherence point before arrive) ----
    __syncthreads();
    if (tid == 0) {
      __hip_atomic_fetch_add(cnt + s, 1u, __ATOMIC_RELAXED, __HIP_MEMORY_SCOPE_AGENT);
      while (__hip_atomic_load(cnt + s, __ATOMIC_RELAXED, __HIP_MEMORY_SCOPE_AGENT) < (u32)NWG) {
        __builtin_amdgcn_s_sleep(1);
      }
    }
    __builtin_amdgcn_sched_barrier(0);
    __syncthreads();
  }
}

extern "C" void kernel_launch(void* const* d_in, const int* in_sizes, int n_in,
                              void* d_out, int out_size, void* d_ws, size_t ws_size,
                              hipStream_t stream) {
  const float* x   = (const float*)d_in[0];
  const float* Wfw = (const float*)d_in[1];
  const float* bfw = (const float*)d_in[2];
  const float* pfw = (const float*)d_in[3];
  const float* Wbw = (const float*)d_in[4];
  const float* bbw = (const float*)d_in[5];
  const float* pbw = (const float*)d_in[6];
  float* out = (float*)d_out;

  char* ws = (char*)d_ws;
  unsigned short* xh   = (unsigned short*)ws;                       // 33,554,432 B
  unsigned short* hbfw = (unsigned short*)(ws + 33554432);          //     98,304 B (2 bufs)
  unsigned short* hbbw = (unsigned short*)(ws + 33554432 + 98304);  //     98,304 B
  u32* cnt             = (u32*)(ws + 33554432 + 2 * 98304);         //      8,192 B

  lstm_init_k<<<104, 256, 0, stream>>>((u32*)hbfw, (u32*)hbbw, cnt);
  lstm_xpose_k<<<16384, 256, 0, stream>>>(x, xh);

  void* kargs[] = {(void*)&Wfw, (void*)&bfw, (void*)&pfw,
                   (void*)&Wbw, (void*)&bbw, (void*)&pbw,
                   (void*)&xh, (void*)&hbfw, (void*)&hbbw,
                   (void*)&cnt, (void*)&out};
  hipError_t err = hipLaunchCooperativeKernel((const void*)lstm_persist_k,
                                              dim3(2 * NWG), dim3(256), kargs, 0, stream);
  if (err != hipSuccess) {
    lstm_persist_k<<<dim3(2 * NWG), dim3(256), 0, stream>>>(Wfw, bfw, pfw, Wbw, bbw, pbw,
                                                            xh, hbfw, hbbw, cnt, out);
  }
}

// Round 4
// 5394.759 us; speedup vs baseline: 4.7889x; 1.2938x over previous
//
#include <hip/hip_runtime.h>
#include <stdint.h>

#define TS   1024
#define NB   32
#define DIN  512
#define HU   768
#define KT   1280
#define NWG  32          // workgroups per direction
#define UPW  24          // hidden units per WG
#define NCT  3           // 32-col MFMA tiles per WG (96 cols)
#define APAD 1288        // As row stride in fp16 (1280+8: row bank-phase shift of 4, <=2-way conflicts)
#define SPIN_MAX 16384

typedef _Float16 f16x8 __attribute__((ext_vector_type(8)));
typedef float f32x16 __attribute__((ext_vector_type(16)));
typedef unsigned int u32;
typedef unsigned long long u64;
typedef u32 u32x4 __attribute__((ext_vector_type(4)));

__device__ __forceinline__ unsigned short f2h_bits(float f) {
  _Float16 h = (_Float16)f;
  return __builtin_bit_cast(unsigned short, h);
}

// ---------------- init: zero h buffers (buf0) and barrier counters ----------------
__global__ void lstm_init_k(u32* hb_fw, u32* hb_bw, u32* ctrl) {
  int i = blockIdx.x * 256 + threadIdx.x;
  const int HB = NB * HU / 2;            // 12288 u32 per h buffer0
  if (i < HB) hb_fw[i] = 0u;
  else if (i < 2 * HB) hb_bw[i - HB] = 0u;
  else if (i < 2 * HB + 512) ctrl[i - 2 * HB] = 0u;
}

// ---------------- transpose + fp16 convert: x[B][T][D] -> xh[T][B][D] ----------------
__global__ void lstm_xpose_k(const float* __restrict__ x, unsigned short* __restrict__ xh) {
  int idx = blockIdx.x * 256 + threadIdx.x;
  int d4 = idx & 127;
  int t  = (idx >> 7) & 1023;
  int b  = idx >> 17;
  float4 v = *(const float4*)(x + ((size_t)(b * TS + t) * DIN + d4 * 4));
  ushort4 o;
  o.x = f2h_bits(v.x); o.y = f2h_bits(v.y); o.z = f2h_bits(v.z); o.w = f2h_bits(v.w);
  *(ushort4*)(xh + ((size_t)(t * NB + b) * DIN + d4 * 4)) = o;
}

#define BAR_LGKM() do { asm volatile("s_waitcnt lgkmcnt(0)" ::: "memory"); \
  __builtin_amdgcn_sched_barrier(0); __builtin_amdgcn_s_barrier(); \
  __builtin_amdgcn_sched_barrier(0); } while (0)
#define BAR_VM0() do { asm volatile("s_waitcnt vmcnt(0) lgkmcnt(0)" ::: "memory"); \
  __builtin_amdgcn_sched_barrier(0); __builtin_amdgcn_s_barrier(); \
  __builtin_amdgcn_sched_barrier(0); } while (0)

// ---------------- persistent bidirectional LSTM scan (64 blocks, plain launch) ----------------
__global__ __launch_bounds__(256, 1) void lstm_persist_k(
    const float* __restrict__ Wfw, const float* __restrict__ bfw, const float* __restrict__ pfw,
    const float* __restrict__ Wbw, const float* __restrict__ bbw, const float* __restrict__ pbw,
    const unsigned short* __restrict__ xh,
    unsigned short* hb_fw, unsigned short* hb_bw,
    u32* ctrl, float* __restrict__ out)
{
  __shared__ __align__(16) unsigned short As[NB * APAD];   // 82,432 B
  __shared__ __align__(16) float Zs[4][NB][100];           // 51,200 B

  const int tid = threadIdx.x;
  const int dir = (blockIdx.x >= NWG) ? 1 : 0;
  const int gg  = blockIdx.x & (NWG - 1);

  const float* W    = dir ? Wbw : Wfw;
  const float* bias = dir ? bbw : bfw;
  const float* peep = dir ? pbw : pfw;
  unsigned short* hbuf = dir ? hb_bw : hb_fw;
  u32* cnt = ctrl + 16 + dir * 128;       // 8 group counters, 64B apart
  const int u0 = gg * UPW;

  const int lane  = tid & 63;
  const int wq    = tid >> 6;      // wave id = K-quarter
  const int colc  = lane & 31;
  const int khalf = lane >> 5;
  const int arow  = colc;          // A-frag row = batch
  const int hrow  = tid >> 3;      // h staging / epilogue row (0..31)
  const int eb    = tid >> 3;

  // ---- preload W slice into registers as MFMA B fragments (240 VGPR) ----
  // tile ct, local col c: gate = c&3, unit = u0 + 8*ct + (c>>2)
  f16x8 wfr[NCT][20];
#pragma unroll
  for (int ct = 0; ct < NCT; ++ct) {
    const int gcol = (colc & 3) * HU + u0 + 8 * ct + (colc >> 2);
#pragma unroll
    for (int ks = 0; ks < 20; ++ks) {
      const int k0 = wq * 320 + ks * 16 + khalf * 8;
#pragma unroll
      for (int j = 0; j < 8; ++j)
        wfr[ct][ks][j] = (_Float16)W[(size_t)(k0 + j) * 3072 + gcol];
    }
  }

  // ---- per-thread epilogue constants: 3 cells (row eb, units u0+(tid&7)+8q) ----
  float bi[3], bj[3], bfc[3], bo[3], pi[3], pfc[3], po[3], cst[3];
#pragma unroll
  for (int q = 0; q < 3; ++q) {
    const int U = u0 + (tid & 7) + 8 * q;
    bi[q] = bias[U]; bj[q] = bias[HU + U]; bfc[q] = bias[2 * HU + U]; bo[q] = bias[3 * HU + U];
    pi[q] = peep[U]; pfc[q] = peep[HU + U]; po[q] = peep[2 * HU + U];
    cst[q] = 0.0f;
  }

  // ---- prologue: x(t0) -> LDS ----
  {
    const unsigned short* x0 = xh + (size_t)(dir ? (TS - 1) : 0) * (NB * DIN);
    u32x4 t[8];
#pragma unroll
    for (int k = 0; k < 8; ++k) t[k] = *(const u32x4*)(x0 + (tid + 256 * k) * 8);
#pragma unroll
    for (int k = 0; k < 8; ++k) {
      const int idx = tid + 256 * k;
      *(u32x4*)(&As[(idx >> 6) * APAD + (idx & 63) * 8]) = t[k];
    }
  }
  u32x4 xr[8];   // x prefetch registers for step s+1

  for (int s = 0; s < TS; ++s) {
    const int t_in = dir ? (TS - 1 - s) : s;
    const u64* hp64 = (const u64*)(hbuf + (s & 1) * (NB * HU));
    u32* hnext32 = (u32*)(hbuf + (((s & 1) ^ 1)) * (NB * HU));

    // ---- P2: h_prev -> LDS (agent-scope u64 loads, R2-proven primitive) ----
#pragma unroll
    for (int half = 0; half < 2; ++half) {
      u64 hv[12];
#pragma unroll
      for (int q = 0; q < 6; ++q) {
        const int c = (tid & 7) + 8 * (q + 6 * half);      // chunk 0..95
        hv[2 * q]     = __hip_atomic_load(hp64 + hrow * 192 + c * 2,
                                          __ATOMIC_RELAXED, __HIP_MEMORY_SCOPE_AGENT);
        hv[2 * q + 1] = __hip_atomic_load(hp64 + hrow * 192 + c * 2 + 1,
                                          __ATOMIC_RELAXED, __HIP_MEMORY_SCOPE_AGENT);
      }
#pragma unroll
      for (int q = 0; q < 6; ++q) {
        const int kc = 64 + (tid & 7) + 8 * (q + 6 * half);
        *(u64*)(&As[hrow * APAD + kc * 8])     = hv[2 * q];
        *(u64*)(&As[hrow * APAD + kc * 8 + 4]) = hv[2 * q + 1];
      }
    }
    BAR_LGKM();   // A-stage complete (x prefetch not drained here)

    // ---- P3: MFMA, 3 col-tiles over this wave's K-quarter ----
    f32x16 a0, a1, a2;
#pragma unroll
    for (int r = 0; r < 16; ++r) { a0[r] = 0.f; a1[r] = 0.f; a2[r] = 0.f; }
#pragma unroll
    for (int ks = 0; ks < 20; ++ks) {
      const int kc = wq * 40 + ks * 2 + khalf;
      const f16x8 av = *(const f16x8*)(&As[arow * APAD + kc * 8]);
      a0 = __builtin_amdgcn_mfma_f32_32x32x16_f16(av, wfr[0][ks], a0, 0, 0, 0);
      a1 = __builtin_amdgcn_mfma_f32_32x32x16_f16(av, wfr[1][ks], a1, 0, 0, 0);
      a2 = __builtin_amdgcn_mfma_f32_32x32x16_f16(av, wfr[2][ks], a2, 0, 0, 0);
    }

    // ---- P4: prefetch x(s+1) into registers (drains at BAR_VM0) ----
    if (s + 1 < TS) {
      const int t_next = dir ? (TS - 2 - s) : (s + 1);
      const unsigned short* xnb = xh + (size_t)t_next * (NB * DIN);
#pragma unroll
      for (int k = 0; k < 8; ++k) xr[k] = *(const u32x4*)(xnb + (tid + 256 * k) * 8);
    }

    // ---- P5: write partial z to LDS ----
    // C/D layout: col=lane&31, row=(r&3)+8*(r>>2)+4*(lane>>5)
#pragma unroll
    for (int r = 0; r < 16; ++r) {
      const int prow = (r & 3) + 8 * (r >> 2) + 4 * khalf;
      Zs[wq][prow][colc]      = a0[r];
      Zs[wq][prow][32 + colc] = a1[r];
      Zs[wq][prow][64 + colc] = a2[r];
    }
    BAR_LGKM();   // Zs ready; As fully consumed

    // ---- P6: epilogue, 3 cells per thread ----
    float hn[3];
#pragma unroll
    for (int q = 0; q < 3; ++q) {
      const int uu = (tid & 7) + 8 * q;
      float zi = 0.f, zj = 0.f, zf = 0.f, zo = 0.f;
#pragma unroll
      for (int qq = 0; qq < 4; ++qq) {
        const float4 zp = *(const float4*)(&Zs[qq][eb][uu * 4]);
        zi += zp.x; zj += zp.y; zf += zp.z; zo += zp.w;
      }
      const float ig = 1.f / (1.f + __expf(-(zi + bi[q] + pi[q] * cst[q])));
      const float fg = 1.f / (1.f + __expf(-(zf + bfc[q] + 1.f + pfc[q] * cst[q])));
      const float jt = 1.f - 2.f / (__expf(2.f * (zj + bj[q])) + 1.f);
      const float cn = fg * cst[q] + ig * jt;
      const float og = 1.f / (1.f + __expf(-(zo + bo[q] + po[q] * cn)));
      hn[q] = og * (1.f - 2.f / (__expf(2.f * cn) + 1.f));
      cst[q] = cn;
    }

    if (s < TS - 1) {
      // h stores: pack fp16 pairs, agent-scope u32 store (R2-proven)
#pragma unroll
      for (int q = 0; q < 3; ++q) {
        const u32 mine  = (u32)f2h_bits(hn[q]);
        const u32 other = (u32)(unsigned)__shfl_xor((int)mine, 1, 64);
        if (!(tid & 1)) {
          __hip_atomic_store(hnext32 + ((eb * HU + u0 + (tid & 7) + 8 * q) >> 1),
                             mine | (other << 16),
                             __ATOMIC_RELAXED, __HIP_MEMORY_SCOPE_AGENT);
        }
      }
      BAR_VM0();      // drain h stores + x prefetch + prev out stores

      // arrive: one no-wait agent add per WG, 8 counters/dir on separate lines
      if (tid == 0)
        (void)__hip_atomic_fetch_add(&cnt[(gg >> 2) * 16], 1u,
                                     __ATOMIC_RELAXED, __HIP_MEMORY_SCOPE_AGENT);

      // out stores off the critical path (drained at next step's BAR_VM0)
#pragma unroll
      for (int q = 0; q < 3; ++q)
        out[((size_t)eb * TS + t_in) * 1536 + dir * HU + u0 + (tid & 7) + 8 * q] = hn[q];

      // P1: staged x(s+1) regs -> LDS (As reads all done at P5 barrier)
#pragma unroll
      for (int k = 0; k < 8; ++k) {
        const int idx = tid + 256 * k;
        *(u32x4*)(&As[(idx >> 6) * APAD + (idx & 63) * 8]) = xr[k];
      }

      // release poll: wave 0, lanes 0..7 poll 8 group counters in parallel (bounded)
      if (wq == 0) {
        const u32 need = 4u * (u32)(s + 1);
        int it = 0; bool ok;
        do {
          u32 v = need;
          if (lane < 8)
            v = __hip_atomic_load(&cnt[lane * 16], __ATOMIC_RELAXED, __HIP_MEMORY_SCOPE_AGENT);
          ok = __all((int)(v >= need));
          if (!ok) __builtin_amdgcn_s_sleep(2);
        } while (!ok && ++it < SPIN_MAX);
      }
      __builtin_amdgcn_sched_barrier(0);
      __builtin_amdgcn_s_barrier();
      __builtin_amdgcn_sched_barrier(0);
    } else {
      // final step: just write out
#pragma unroll
      for (int q = 0; q < 3; ++q)
        out[((size_t)eb * TS + t_in) * 1536 + dir * HU + u0 + (tid & 7) + 8 * q] = hn[q];
    }
  }
}

extern "C" void kernel_launch(void* const* d_in, const int* in_sizes, int n_in,
                              void* d_out, int out_size, void* d_ws, size_t ws_size,
                              hipStream_t stream) {
  const float* x   = (const float*)d_in[0];
  const float* Wfw = (const float*)d_in[1];
  const float* bfw = (const float*)d_in[2];
  const float* pfw = (const float*)d_in[3];
  const float* Wbw = (const float*)d_in[4];
  const float* bbw = (const float*)d_in[5];
  const float* pbw = (const float*)d_in[6];
  float* out = (float*)d_out;

  char* ws = (char*)d_ws;
  unsigned short* xh   = (unsigned short*)ws;                       // 33,554,432 B
  unsigned short* hbfw = (unsigned short*)(ws + 33554432);          //     98,304 B (2 bufs)
  unsigned short* hbbw = (unsigned short*)(ws + 33554432 + 98304);  //     98,304 B
  u32* ctrl            = (u32*)(ws + 33554432 + 2 * 98304);         //      2,048 B

  lstm_init_k<<<97, 256, 0, stream>>>((u32*)hbfw, (u32*)hbbw, ctrl);
  lstm_xpose_k<<<16384, 256, 0, stream>>>(x, xh);
  lstm_persist_k<<<dim3(2 * NWG), dim3(256), 0, stream>>>(Wfw, bfw, pfw, Wbw, bbw, pbw,
                                                          xh, hbfw, hbbw, ctrl, out);
}